// Round 12
// baseline (109.930 us; speedup 1.0000x reference)
//
#include <hip/hip_runtime.h>
#include <float.h>

#define NT 32768
#define DIM 2048
#define NE 64
#define TAU 1e-3f
#define TPB 32              // tokens per block
#define CHUNK 64
#define NCH (DIM / CHUNK)   // 32 chunks

typedef __attribute__((ext_vector_type(8))) short short8;
typedef __attribute__((ext_vector_type(4))) float f32x4;

__device__ __forceinline__ unsigned short f2bf(float f) {
    unsigned u = __float_as_uint(f);
    u += 0x7fffu + ((u >> 16) & 1u);          // RNE
    return (unsigned short)(u >> 16);
}
__device__ __forceinline__ float bf2f(unsigned short h) {
    return __uint_as_float(((unsigned)h) << 16);
}

// Pack gw into MFMA-B fragment order, split hi/lo bf16 (RNE):
// wpk[et][ksg][lane][j] = gw[et*16 + (lane&15)][ksg*32 + (lane>>4)*8 + j]
__global__ __launch_bounds__(256)
void prep_w(const float* __restrict__ gw, unsigned short* __restrict__ wph,
            unsigned short* __restrict__ wpl, int* __restrict__ cnt) {
    const int gid  = blockIdx.x * 256 + threadIdx.x;   // 16384 threads
    const int lane = gid & 63;
    const int ksg  = (gid >> 6) & 63;
    const int et   = gid >> 12;
    const int e    = et * 16 + (lane & 15);
    const int k0   = ksg * 32 + (lane >> 4) * 8;

    float4 v0 = *(const float4*)(gw + (size_t)e * DIM + k0);
    float4 v1 = *(const float4*)(gw + (size_t)e * DIM + k0 + 4);
    float xf[8] = {v0.x, v0.y, v0.z, v0.w, v1.x, v1.y, v1.z, v1.w};
    short8 h, l;
#pragma unroll
    for (int j = 0; j < 8; ++j) {
        unsigned short hh = f2bf(xf[j]);
        h[j] = (short)hh;
        l[j] = (short)f2bf(xf[j] - bf2f(hh));
    }
    *(short8*)(wph + (size_t)gid * 8) = h;
    *(short8*)(wpl + (size_t)gid * 8) = l;
    if (gid == 0) *cnt = 0;
}

__global__ __launch_bounds__(256, 4)
void router_mfma(const float* __restrict__ x,
                 const unsigned short* __restrict__ wph,
                 const unsigned short* __restrict__ wpl,
                 float* __restrict__ out,
                 int* __restrict__ cnt, int* __restrict__ list) {
    // 16 KB: 2 dbuf x {hi 4K, lo 4K}; epilogue aliases float lm[32][68] (8.7 KB)
    __shared__ __align__(16) unsigned char smem[16384];

    const int tid  = threadIdx.x;
    const int lane = tid & 63;
    const int wid  = tid >> 6;
    const int tg   = wid >> 1;                 // token half 0..1
    const int eg   = wid & 1;                  // expert half 0..1
    const int t0   = blockIdx.x * TPB;

    // staging coords: thread (r = token 0..31, sq = k-octet 0..7)
    const int r  = tid >> 3;
    const int sq = tid & 7;
    const int g  = r >> 4;                      // subtile
    const int sr = r & 15;
    const unsigned swoff = (unsigned)((sr * 128 + sq * 16) ^ ((sr & 7) << 4));
    const float* xbase = x + (size_t)(t0 + r) * DIM + sq * 8;
    unsigned char* stb = smem + g * 2048 + swoff;   // hi plane; lo at +4096

    // compute-side swizzled read offsets (ks = 0 / 1)
    const unsigned roff0 = (unsigned)((((lane & 15) * 128) | ((lane >> 4) << 4))
                                      ^ ((lane & 7) << 4));
    const unsigned roff1 = roff0 ^ 64u;

    f32x4 accP[2], accQ[2];
#pragma unroll
    for (int e = 0; e < 2; ++e)
#pragma unroll
        for (int j = 0; j < 4; ++j) { accP[e][j] = 0.f; accQ[e][j] = 0.f; }

    float4 xr0, xr1;
    short8 Bh[2][2], Bl[2][2];                 // [e][ks], JIT per chunk

#define LOADX(c_) { xr0 = *(const float4*)(xbase + (c_) * CHUNK); \
                    xr1 = *(const float4*)(xbase + (c_) * CHUNK + 4); }

#define BLOAD(c_) { _Pragma("unroll") for (int e = 0; e < 2; ++e) \
    _Pragma("unroll") for (int ks = 0; ks < 2; ++ks) { \
        size_t o_ = (((size_t)(eg * 2 + e) * 64 + ((c_) * 2 + ks)) * 64 + lane) * 8; \
        Bh[e][ks] = *(const short8*)(wph + o_); \
        Bl[e][ks] = *(const short8*)(wpl + o_); } }

// truncation split: hi = top16(x), lo = top16(x - hi)
#define CVT_STORE(buf_) { \
        unsigned u0 = __float_as_uint(xr0.x), u1 = __float_as_uint(xr0.y); \
        unsigned u2 = __float_as_uint(xr0.z), u3 = __float_as_uint(xr0.w); \
        unsigned u4 = __float_as_uint(xr1.x), u5 = __float_as_uint(xr1.y); \
        unsigned u6 = __float_as_uint(xr1.z), u7 = __float_as_uint(xr1.w); \
        float l0 = xr0.x - __uint_as_float(u0 & 0xffff0000u); \
        float l1 = xr0.y - __uint_as_float(u1 & 0xffff0000u); \
        float l2 = xr0.z - __uint_as_float(u2 & 0xffff0000u); \
        float l3 = xr0.w - __uint_as_float(u3 & 0xffff0000u); \
        float l4 = xr1.x - __uint_as_float(u4 & 0xffff0000u); \
        float l5 = xr1.y - __uint_as_float(u5 & 0xffff0000u); \
        float l6 = xr1.z - __uint_as_float(u6 & 0xffff0000u); \
        float l7 = xr1.w - __uint_as_float(u7 & 0xffff0000u); \
        ushort4 h0_ = make_ushort4((unsigned short)(u0 >> 16), (unsigned short)(u1 >> 16), \
                                   (unsigned short)(u2 >> 16), (unsigned short)(u3 >> 16)); \
        ushort4 h1_ = make_ushort4((unsigned short)(u4 >> 16), (unsigned short)(u5 >> 16), \
                                   (unsigned short)(u6 >> 16), (unsigned short)(u7 >> 16)); \
        ushort4 lo0_ = make_ushort4((unsigned short)(__float_as_uint(l0) >> 16), \
                                    (unsigned short)(__float_as_uint(l1) >> 16), \
                                    (unsigned short)(__float_as_uint(l2) >> 16), \
                                    (unsigned short)(__float_as_uint(l3) >> 16)); \
        ushort4 lo1_ = make_ushort4((unsigned short)(__float_as_uint(l4) >> 16), \
                                    (unsigned short)(__float_as_uint(l5) >> 16), \
                                    (unsigned short)(__float_as_uint(l6) >> 16), \
                                    (unsigned short)(__float_as_uint(l7) >> 16)); \
        unsigned char* p_ = stb + (buf_) * 8192; \
        *(ushort4*)(p_)          = h0_;  *(ushort4*)(p_ + 8)        = h1_; \
        *(ushort4*)(p_ + 4096)   = lo0_; *(ushort4*)(p_ + 4096 + 8) = lo1_; }

#define MFMA_PHASE(buf_) { _Pragma("unroll") for (int ks = 0; ks < 2; ++ks) { \
        const unsigned char* pa_ = smem + (buf_) * 8192 + tg * 2048 \
                                   + (ks ? roff1 : roff0); \
        short8 Ah_ = *(const short8*)pa_; \
        short8 Al_ = *(const short8*)(pa_ + 4096); \
        _Pragma("unroll") for (int e = 0; e < 2; ++e) { \
            accP[e] = __builtin_amdgcn_mfma_f32_16x16x32_bf16(Ah_, Bh[e][ks], accP[e], 0, 0, 0); \
            accQ[e] = __builtin_amdgcn_mfma_f32_16x16x32_bf16(Ah_, Bl[e][ks], accQ[e], 0, 0, 0); \
            accQ[e] = __builtin_amdgcn_mfma_f32_16x16x32_bf16(Al_, Bh[e][ks], accQ[e], 0, 0, 0); } } }

    // prologue: stage chunk 0
    LOADX(0)
    CVT_STORE(0)
    __syncthreads();

#pragma unroll 1
    for (int c = 0; c < NCH; ++c) {
        if (c + 1 < NCH) LOADX(c + 1)
        BLOAD(c)
        MFMA_PHASE(c & 1)
        if (c + 1 < NCH) CVT_STORE((c + 1) & 1)
        __syncthreads();
    }
#undef LOADX
#undef BLOAD
#undef CVT_STORE
#undef MFMA_PHASE

    // merge logits into aliased LDS (staging buffers dead after final sync)
    float* lmf = (float*)smem;                 // [32][68]
#pragma unroll
    for (int e = 0; e < 2; ++e)
#pragma unroll
        for (int jr = 0; jr < 4; ++jr)
            lmf[(tg * 16 + (lane >> 4) * 4 + jr) * 68 + eg * 32 + e * 16 + (lane & 15)] =
                accP[e][jr] + accQ[e][jr];
    __syncthreads();

    // ---- epilogue: 8 threads per token, 8 experts each ----
    float* mout = out;
    float* wout = out + (size_t)NT * NE;
    float* iout = wout + (size_t)NT * 2;

    const int t   = tid >> 3;                  // local token 0..31
    const int s   = tid & 7;                   // 8-expert segment
    const int tok = t0 + t;

    float vv[8];
    {
        float4 p0 = *(const float4*)&lmf[t * 68 + s * 8];
        float4 p1 = *(const float4*)&lmf[t * 68 + s * 8 + 4];
        vv[0] = p0.x; vv[1] = p0.y; vv[2] = p0.z; vv[3] = p0.w;
        vv[4] = p1.x; vv[5] = p1.y; vv[6] = p1.z; vv[7] = p1.w;
    }

    float m1 = -FLT_MAX, m2 = -FLT_MAX, m3 = -FLT_MAX;
    int   i1 = NE, i2 = NE, i3 = NE;
    auto ins = [&](float v, int e) {
        bool b1 = (v > m1) || (v == m1 && e < i1);
        bool b2 = (v > m2) || (v == m2 && e < i2);
        bool b3 = (v > m3) || (v == m3 && e < i3);
        if (b1)      { m3 = m2; i3 = i2; m2 = m1; i2 = i1; m1 = v; i1 = e; }
        else if (b2) { m3 = m2; i3 = i2; m2 = v; i2 = e; }
        else if (b3) { m3 = v; i3 = e; }
    };
#pragma unroll
    for (int j = 0; j < 8; ++j) ins(vv[j], s * 8 + j);
#pragma unroll
    for (int off = 1; off <= 4; off <<= 1) {   // merge across the 8-lane group
        float om1 = __shfl_xor(m1, off, 64); int oi1 = __shfl_xor(i1, off, 64);
        float om2 = __shfl_xor(m2, off, 64); int oi2 = __shfl_xor(i2, off, 64);
        float om3 = __shfl_xor(m3, off, 64); int oi3 = __shfl_xor(i3, off, 64);
        ins(om1, oi1); ins(om2, oi2); ins(om3, oi3);
    }

    float ed  = expf(m2 - m1);
    float inv = 1.f / (1.f + ed);

    {
        float4 mv0, mv1;
        int e0 = s * 8;
        mv0.x = (e0     == i1 || e0     == i2) ? 1.f : 0.f;
        mv0.y = (e0 + 1 == i1 || e0 + 1 == i2) ? 1.f : 0.f;
        mv0.z = (e0 + 2 == i1 || e0 + 2 == i2) ? 1.f : 0.f;
        mv0.w = (e0 + 3 == i1 || e0 + 3 == i2) ? 1.f : 0.f;
        mv1.x = (e0 + 4 == i1 || e0 + 4 == i2) ? 1.f : 0.f;
        mv1.y = (e0 + 5 == i1 || e0 + 5 == i2) ? 1.f : 0.f;
        mv1.z = (e0 + 6 == i1 || e0 + 6 == i2) ? 1.f : 0.f;
        mv1.w = (e0 + 7 == i1 || e0 + 7 == i2) ? 1.f : 0.f;
        *(float4*)(mout + (size_t)tok * NE + e0)     = mv0;
        *(float4*)(mout + (size_t)tok * NE + e0 + 4) = mv1;
    }

    if (s == 0) {
        *(float2*)(wout + 2 * tok) = make_float2(inv, ed * inv);
        *(float2*)(iout + 2 * tok) = make_float2((float)i1, (float)i2);
        if ((m1 - m2 < TAU) || (m2 - m3 < TAU)) {
            int slot = atomicAdd(cnt, 1);
            list[slot] = tok;
        }
    }
}

// Exact fp32 recompute of flagged (near-tie) tokens; overwrites their outputs.
__global__ __launch_bounds__(256)
void repair(const float* __restrict__ x, const float* __restrict__ gw,
            float* __restrict__ out, const int* __restrict__ cnt,
            const int* __restrict__ list) {
    __shared__ float red[64][5];
    const int n   = *cnt;
    const int tid = threadIdx.x;
    const int e   = tid & 63, qq = tid >> 6;     // expert, k-quarter

    float* mout = out;
    float* wout = out + (size_t)NT * NE;
    float* iout = wout + (size_t)NT * 2;

    for (int i = blockIdx.x; i < n; i += gridDim.x) {
        const int tok = list[i];
        const float* xr = x + (size_t)tok * DIM + qq * 512;
        const float* wr = gw + (size_t)e * DIM + qq * 512;
        float a = 0.f;
        for (int j = 0; j < 512; j += 4) {
            float4 xv = *(const float4*)(xr + j);
            float4 wv = *(const float4*)(wr + j);
            a = fmaf(xv.x, wv.x, a); a = fmaf(xv.y, wv.y, a);
            a = fmaf(xv.z, wv.z, a); a = fmaf(xv.w, wv.w, a);
        }
        red[e][qq] = a;
        __syncthreads();
        if (tid < 64) {
            float v = ((red[e][0] + red[e][1]) + red[e][2]) + red[e][3];
            float m1 = v, m2 = -FLT_MAX; int i1 = e, i2 = NE;
#pragma unroll
            for (int off = 1; off <= 32; off <<= 1) {
                float om1 = __shfl_xor(m1, off, 64); int oi1 = __shfl_xor(i1, off, 64);
                float om2 = __shfl_xor(m2, off, 64); int oi2 = __shfl_xor(i2, off, 64);
                bool selfFirst = (m1 > om1) || (m1 == om1 && i1 < oi1);
                if (selfFirst) {
                    if (!((m2 > om1) || (m2 == om1 && i2 < oi1))) { m2 = om1; i2 = oi1; }
                } else {
                    bool c = (m1 > om2) || (m1 == om2 && i1 < oi2);
                    if (c) { m2 = m1; i2 = i1; } else { m2 = om2; i2 = oi2; }
                    m1 = om1; i1 = oi1;
                }
            }
            float ed  = expf(m2 - m1);
            float inv = 1.f / (1.f + ed);
            mout[(size_t)tok * NE + e] = (e == i1 || e == i2) ? 1.f : 0.f;
            if (e == 0) {
                *(float2*)(wout + 2 * tok) = make_float2(inv, ed * inv);
                *(float2*)(iout + 2 * tok) = make_float2((float)i1, (float)i2);
            }
        }
        __syncthreads();
    }
}

extern "C" void kernel_launch(void* const* d_in, const int* in_sizes, int n_in,
                              void* d_out, int out_size, void* d_ws, size_t ws_size,
                              hipStream_t stream) {
    const float* x  = (const float*)d_in[0];
    const float* gw = (const float*)d_in[1];
    float* out = (float*)d_out;

    unsigned short* wph = (unsigned short*)d_ws;         // 256 KB (packed hi)
    unsigned short* wpl = wph + (size_t)NE * DIM;        // 256 KB (packed lo)
    int* cnt  = (int*)(wpl + (size_t)NE * DIM);          // 4 B
    int* list = cnt + 1;                                 // 128 KB

    prep_w<<<dim3(64), dim3(256), 0, stream>>>(gw, wph, wpl, cnt);
    router_mfma<<<dim3(NT / TPB), dim3(256), 0, stream>>>(x, wph, wpl, out, cnt, list);
    repair<<<dim3(256), dim3(256), 0, stream>>>(x, gw, out, cnt, list);
}

// Round 13
// 93.393 us; speedup vs baseline: 1.1771x; 1.1771x over previous
//
#include <hip/hip_runtime.h>
#include <float.h>

#define NT 32768
#define DIM 2048
#define NE 64
#define TAU 1e-3f
#define CHUNK 128
#define NCH (DIM / CHUNK)   // 16 chunks

typedef __attribute__((ext_vector_type(8))) short short8;
typedef __attribute__((ext_vector_type(4))) float f32x4;

__device__ __forceinline__ unsigned short f2bf(float f) {
    unsigned u = __float_as_uint(f);
    u += 0x7fffu + ((u >> 16) & 1u);          // RNE
    return (unsigned short)(u >> 16);
}
__device__ __forceinline__ float bf2f(unsigned short h) {
    return __uint_as_float(((unsigned)h) << 16);
}

// Pack gw into MFMA-B fragment order, split hi/lo bf16 (RNE):
// wpk[et][ksg][lane][j] = gw[et*16 + (lane&15)][ksg*32 + (lane>>4)*8 + j]
__global__ __launch_bounds__(256)
void prep_w(const float* __restrict__ gw, unsigned short* __restrict__ wph,
            unsigned short* __restrict__ wpl, int* __restrict__ cnt) {
    const int gid  = blockIdx.x * 256 + threadIdx.x;   // 16384 threads
    const int lane = gid & 63;
    const int ksg  = (gid >> 6) & 63;
    const int et   = gid >> 12;
    const int e    = et * 16 + (lane & 15);
    const int k0   = ksg * 32 + (lane >> 4) * 8;

    float4 v0 = *(const float4*)(gw + (size_t)e * DIM + k0);
    float4 v1 = *(const float4*)(gw + (size_t)e * DIM + k0 + 4);
    float xf[8] = {v0.x, v0.y, v0.z, v0.w, v1.x, v1.y, v1.z, v1.w};
    short8 h, l;
#pragma unroll
    for (int j = 0; j < 8; ++j) {
        unsigned short hh = f2bf(xf[j]);
        h[j] = (short)hh;
        l[j] = (short)f2bf(xf[j] - bf2f(hh));
    }
    *(short8*)(wph + (size_t)gid * 8) = h;
    *(short8*)(wpl + (size_t)gid * 8) = l;
    if (gid == 0) *cnt = 0;
}

__global__ __launch_bounds__(256, 2)
void router_mfma(const float* __restrict__ x,
                 const unsigned short* __restrict__ wph,
                 const unsigned short* __restrict__ wpl,
                 float* __restrict__ out,
                 int* __restrict__ cnt, int* __restrict__ list) {
    // 64 KB: 2 dbuf x {hi plane 16K, lo plane 16K}; epilogue aliases float lm[64][68]
    __shared__ __align__(16) unsigned char smem[65536];

    const int tid  = threadIdx.x;
    const int lane = tid & 63;
    const int et   = tid >> 6;                 // wave == 16-expert tile
    const int t0   = blockIdx.x * 64;

    // staging coords: thread (sr = token row 0..15, sq = k-quad 0..15)
    const int sr = tid >> 4;
    const int sq = tid & 15;
    const unsigned swoff = (unsigned)((sr * 128 + sq * 8) ^ ((sr & 7) << 4));
    const float* xbase = x + (size_t)(t0 + sr) * DIM + sq * 4;

    // compute-side swizzled read offsets (ks even / odd)
    const unsigned roff_e = (unsigned)((((lane & 15) * 128) | ((lane >> 4) << 4))
                                       ^ ((lane & 7) << 4));
    const unsigned roff_o = roff_e ^ 64u;

    f32x4 accP[4], accQ[4];
#pragma unroll
    for (int tt = 0; tt < 4; ++tt)
#pragma unroll
        for (int j = 0; j < 4; ++j) { accP[tt][j] = 0.f; accQ[tt][j] = 0.f; }

    float4 xrA[8], xrB[8];                     // depth-2 x prefetch banks
    short8 Bh0[4], Bl0[4], Bh1[4], Bl1[4];

#define LOADX(bank_, c_) { _Pragma("unroll") for (int tt = 0; tt < 4; ++tt) \
    _Pragma("unroll") for (int i = 0; i < 2; ++i) \
        xr##bank_[tt*2+i] = *(const float4*)(xbase + (size_t)tt * 16 * DIM + (c_) * CHUNK + i * 64); }

#define BLOAD(bk_, c_) { _Pragma("unroll") for (int ksg = 0; ksg < 4; ++ksg) { \
        size_t o_ = (((size_t)et * 64 + ((c_) * 4 + ksg)) * 64 + lane) * 8; \
        Bh##bk_[ksg] = *(const short8*)(wph + o_); \
        Bl##bk_[ksg] = *(const short8*)(wpl + o_); } }

// truncation split: hi = top16(x), lo = top16(x - hi)
#define CVT_STORE(bank_, buf_) { _Pragma("unroll") for (int tt = 0; tt < 4; ++tt) \
    _Pragma("unroll") for (int i = 0; i < 2; ++i) { \
        float4 v_ = xr##bank_[tt*2+i]; \
        unsigned u0 = __float_as_uint(v_.x), u1 = __float_as_uint(v_.y); \
        unsigned u2 = __float_as_uint(v_.z), u3 = __float_as_uint(v_.w); \
        float l0 = v_.x - __uint_as_float(u0 & 0xffff0000u); \
        float l1 = v_.y - __uint_as_float(u1 & 0xffff0000u); \
        float l2 = v_.z - __uint_as_float(u2 & 0xffff0000u); \
        float l3 = v_.w - __uint_as_float(u3 & 0xffff0000u); \
        ushort4 hv_ = make_ushort4((unsigned short)(u0 >> 16), (unsigned short)(u1 >> 16), \
                                   (unsigned short)(u2 >> 16), (unsigned short)(u3 >> 16)); \
        ushort4 lv_ = make_ushort4((unsigned short)(__float_as_uint(l0) >> 16), \
                                   (unsigned short)(__float_as_uint(l1) >> 16), \
                                   (unsigned short)(__float_as_uint(l2) >> 16), \
                                   (unsigned short)(__float_as_uint(l3) >> 16)); \
        unsigned char* p_ = smem + (buf_) * 32768 + (tt*2+i) * 2048 + swoff; \
        *(ushort4*)p_ = hv_; \
        *(ushort4*)(p_ + 16384) = lv_; } }

#define MFMA_PHASE(buf_, bk_) { _Pragma("unroll") for (int ks = 0; ks < 4; ++ks) { \
        const unsigned ro_ = (ks & 1) ? roff_o : roff_e; \
        _Pragma("unroll") for (int tt = 0; tt < 4; ++tt) { \
            const unsigned char* pa_ = smem + (buf_) * 32768 + tt * 4096 + (ks >> 1) * 2048 + ro_; \
            short8 Ah_ = *(const short8*)pa_; \
            short8 Al_ = *(const short8*)(pa_ + 16384); \
            accP[tt] = __builtin_amdgcn_mfma_f32_16x16x32_bf16(Ah_, Bh##bk_[ks], accP[tt], 0, 0, 0); \
            accQ[tt] = __builtin_amdgcn_mfma_f32_16x16x32_bf16(Ah_, Bl##bk_[ks], accQ[tt], 0, 0, 0); \
            accQ[tt] = __builtin_amdgcn_mfma_f32_16x16x32_bf16(Al_, Bh##bk_[ks], accQ[tt], 0, 0, 0); } } }

// T3/T4: LDS-only wait + raw barrier -> global prefetches stay in flight
#define BARSYNC { asm volatile("s_waitcnt lgkmcnt(0)" ::: "memory"); \
                  __builtin_amdgcn_sched_barrier(0); \
                  __builtin_amdgcn_s_barrier(); }

    // prologue: chunks 0,1 in flight; chunk 0 staged; B(0) in bank 0
    LOADX(A, 0)
    LOADX(B, 1)
    BLOAD(0, 0)
    CVT_STORE(A, 0)
    BARSYNC

    // steady state: c = 0..13, branch-free bodies (7 even/odd pairs)
#pragma unroll 1
    for (int cc = 0; cc < 7; ++cc) {
        const int c0 = 2 * cc;                 // even chunk, c0 <= 12
        LOADX(A, c0 + 2)
        BLOAD(1, c0 + 1)
        MFMA_PHASE(0, 0)
        CVT_STORE(B, 1)
        BARSYNC
        const int c1 = c0 + 1;                 // odd chunk, c1 <= 13
        LOADX(B, c1 + 2)
        BLOAD(0, c1 + 1)
        MFMA_PHASE(1, 1)
        CVT_STORE(A, 0)
        BARSYNC
    }
    // tail c = 14: no LOADX
    BLOAD(1, 15)
    MFMA_PHASE(0, 0)
    CVT_STORE(B, 1)
    BARSYNC
    // tail c = 15: MFMA only (reads buf1; merge below writes buf0 region - disjoint)
    MFMA_PHASE(1, 1)

#undef LOADX
#undef BLOAD
#undef CVT_STORE
#undef MFMA_PHASE
#undef BARSYNC

    // merge logits into aliased LDS (buf0 region last read before previous barrier)
    float* lmf = (float*)smem;                 // [64][68]
#pragma unroll
    for (int tt = 0; tt < 4; ++tt)
#pragma unroll
        for (int jr = 0; jr < 4; ++jr)
            lmf[(tt * 16 + (lane >> 4) * 4 + jr) * 68 + et * 16 + (lane & 15)] =
                accP[tt][jr] + accQ[tt][jr];
    __syncthreads();

    // ---- epilogue: 4 threads per token, 16 experts each ----
    float* mout = out;
    float* wout = out + (size_t)NT * NE;
    float* iout = wout + (size_t)NT * 2;

    const int t   = tid >> 2;                  // local token 0..63
    const int s   = tid & 3;                   // 16-expert segment
    const int tok = t0 + t;

    float vv[16];
#pragma unroll
    for (int j4 = 0; j4 < 4; ++j4) {
        float4 pv = *(const float4*)&lmf[t * 68 + s * 16 + j4 * 4];
        vv[j4 * 4] = pv.x; vv[j4 * 4 + 1] = pv.y; vv[j4 * 4 + 2] = pv.z; vv[j4 * 4 + 3] = pv.w;
    }

    float m1 = -FLT_MAX, m2 = -FLT_MAX, m3 = -FLT_MAX;
    int   i1 = NE, i2 = NE, i3 = NE;
    auto ins = [&](float v, int e) {
        bool b1 = (v > m1) || (v == m1 && e < i1);
        bool b2 = (v > m2) || (v == m2 && e < i2);
        bool b3 = (v > m3) || (v == m3 && e < i3);
        if (b1)      { m3 = m2; i3 = i2; m2 = m1; i2 = i1; m1 = v; i1 = e; }
        else if (b2) { m3 = m2; i3 = i2; m2 = v; i2 = e; }
        else if (b3) { m3 = v; i3 = e; }
    };
#pragma unroll
    for (int j = 0; j < 16; ++j) ins(vv[j], s * 16 + j);
#pragma unroll
    for (int off = 1; off <= 2; off <<= 1) {   // merge across the 4-lane group
        float om1 = __shfl_xor(m1, off, 64); int oi1 = __shfl_xor(i1, off, 64);
        float om2 = __shfl_xor(m2, off, 64); int oi2 = __shfl_xor(i2, off, 64);
        float om3 = __shfl_xor(m3, off, 64); int oi3 = __shfl_xor(i3, off, 64);
        ins(om1, oi1); ins(om2, oi2); ins(om3, oi3);
    }

    float ed  = expf(m2 - m1);
    float inv = 1.f / (1.f + ed);

#pragma unroll
    for (int j4 = 0; j4 < 4; ++j4) {
        float4 mv;
        int e0 = s * 16 + j4 * 4;
        mv.x = (e0     == i1 || e0     == i2) ? 1.f : 0.f;
        mv.y = (e0 + 1 == i1 || e0 + 1 == i2) ? 1.f : 0.f;
        mv.z = (e0 + 2 == i1 || e0 + 2 == i2) ? 1.f : 0.f;
        mv.w = (e0 + 3 == i1 || e0 + 3 == i2) ? 1.f : 0.f;
        *(float4*)(mout + (size_t)tok * NE + e0) = mv;
    }

    if (s == 0) {
        *(float2*)(wout + 2 * tok) = make_float2(inv, ed * inv);
        *(float2*)(iout + 2 * tok) = make_float2((float)i1, (float)i2);
        if ((m1 - m2 < TAU) || (m2 - m3 < TAU)) {
            int slot = atomicAdd(cnt, 1);
            list[slot] = tok;
        }
    }
}

// Exact fp32 recompute of flagged (near-tie) tokens; overwrites their outputs.
__global__ __launch_bounds__(256)
void repair(const float* __restrict__ x, const float* __restrict__ gw,
            float* __restrict__ out, const int* __restrict__ cnt,
            const int* __restrict__ list) {
    __shared__ float red[64][5];
    const int n   = *cnt;
    const int tid = threadIdx.x;
    const int e   = tid & 63, qq = tid >> 6;     // expert, k-quarter

    float* mout = out;
    float* wout = out + (size_t)NT * NE;
    float* iout = wout + (size_t)NT * 2;

    for (int i = blockIdx.x; i < n; i += gridDim.x) {
        const int tok = list[i];
        const float* xr = x + (size_t)tok * DIM + qq * 512;
        const float* wr = gw + (size_t)e * DIM + qq * 512;
        float a = 0.f;
        for (int j = 0; j < 512; j += 4) {
            float4 xv = *(const float4*)(xr + j);
            float4 wv = *(const float4*)(wr + j);
            a = fmaf(xv.x, wv.x, a); a = fmaf(xv.y, wv.y, a);
            a = fmaf(xv.z, wv.z, a); a = fmaf(xv.w, wv.w, a);
        }
        red[e][qq] = a;
        __syncthreads();
        if (tid < 64) {
            float v = ((red[e][0] + red[e][1]) + red[e][2]) + red[e][3];
            float m1 = v, m2 = -FLT_MAX; int i1 = e, i2 = NE;
#pragma unroll
            for (int off = 1; off <= 32; off <<= 1) {
                float om1 = __shfl_xor(m1, off, 64); int oi1 = __shfl_xor(i1, off, 64);
                float om2 = __shfl_xor(m2, off, 64); int oi2 = __shfl_xor(i2, off, 64);
                bool selfFirst = (m1 > om1) || (m1 == om1 && i1 < oi1);
                if (selfFirst) {
                    if (!((m2 > om1) || (m2 == om1 && i2 < oi1))) { m2 = om1; i2 = oi1; }
                } else {
                    bool c = (m1 > om2) || (m1 == om2 && i1 < oi2);
                    if (c) { m2 = m1; i2 = i1; } else { m2 = om2; i2 = oi2; }
                    m1 = om1; i1 = oi1;
                }
            }
            float ed  = expf(m2 - m1);
            float inv = 1.f / (1.f + ed);
            mout[(size_t)tok * NE + e] = (e == i1 || e == i2) ? 1.f : 0.f;
            if (e == 0) {
                *(float2*)(wout + 2 * tok) = make_float2(inv, ed * inv);
                *(float2*)(iout + 2 * tok) = make_float2((float)i1, (float)i2);
            }
        }
        __syncthreads();
    }
}

extern "C" void kernel_launch(void* const* d_in, const int* in_sizes, int n_in,
                              void* d_out, int out_size, void* d_ws, size_t ws_size,
                              hipStream_t stream) {
    const float* x  = (const float*)d_in[0];
    const float* gw = (const float*)d_in[1];
    float* out = (float*)d_out;

    unsigned short* wph = (unsigned short*)d_ws;         // 256 KB (packed hi)
    unsigned short* wpl = wph + (size_t)NE * DIM;        // 256 KB (packed lo)
    int* cnt  = (int*)(wpl + (size_t)NE * DIM);          // 4 B
    int* list = cnt + 1;                                 // 128 KB

    prep_w<<<dim3(64), dim3(256), 0, stream>>>(gw, wph, wpl, cnt);
    router_mfma<<<dim3(NT / 64), dim3(256), 0, stream>>>(x, wph, wpl, out, cnt, list);
    repair<<<dim3(256), dim3(256), 0, stream>>>(x, gw, out, cnt, list);
}